// Round 1
// baseline (273.382 us; speedup 1.0000x reference)
//
#include <hip/hip_runtime.h>
#include <math.h>

// YOLOv2 loss: pred/target (16,52,52,5,85) fp32 -> scalar fp32.
// N=16, S=52, A=5, C=80. Wave-per-cell, 4 cells/block, float4 LDS staging.

#define NIMG   16
#define SDIM   52
#define NA     5
#define NC     80
#define STRIDE 85                 // 5+C
#define CELLF  (NA * STRIDE)      // 425 floats per cell
#define NCELLS (NIMG * SDIM * SDIM) // 43264
#define CPB    4                  // cells per block (1 per wave)

__device__ __constant__ float AW[5] = {0.57273f, 1.87446f, 3.33843f, 7.88282f, 9.77052f};
__device__ __constant__ float AH[5] = {0.677385f, 2.06253f, 5.47434f, 3.52778f, 9.16828f};

__device__ inline float waveMax(float v) {
#pragma unroll
    for (int o = 32; o; o >>= 1) v = fmaxf(v, __shfl_xor(v, o));
    return v;
}
__device__ inline float waveSum(float v) {
#pragma unroll
    for (int o = 32; o; o >>= 1) v += __shfl_xor(v, o);
    return v;
}
__device__ inline float softplusf(float x) {
    // log(1+exp(x)) stable
    return fmaxf(x, 0.0f) + log1pf(expf(-fabsf(x)));
}
__device__ inline float sigmoidf(float x) { return 1.0f / (1.0f + expf(-x)); }

__global__ __launch_bounds__(256) void yolo_loss_kernel(
    const float* __restrict__ pred, const float* __restrict__ target,
    float* __restrict__ out) {
    __shared__ float4 spv[CPB * CELLF / 4];   // 425 float4 = 4 cells of pred
    __shared__ float4 stv[CPB * CELLF / 4];
    __shared__ float wsum[CPB];

    const int tid = threadIdx.x;
    const size_t blk4 = (size_t)blockIdx.x * (CPB * CELLF / 4);
    const float4* gp = reinterpret_cast<const float4*>(pred) + blk4;
    const float4* gt = reinterpret_cast<const float4*>(target) + blk4;
#pragma unroll
    for (int i = tid; i < CPB * CELLF / 4; i += 256) {
        spv[i] = gp[i];
        stv[i] = gt[i];
    }
    __syncthreads();

    const int w = tid >> 6;
    const int lane = tid & 63;
    const float* P = reinterpret_cast<const float*>(spv) + w * CELLF;
    const float* T = reinterpret_cast<const float*>(stv) + w * CELLF;

    // ---- per-anchor decoded values (redundant on all 64 lanes; wave-uniform)
    float sx[NA], sy[NA], ptw[NA], pth[NA], pto[NA];
    float px1[NA], px2[NA], py1[NA], py2[NA];     // pred box corners
    float gx[NA], gy[NA];
    float gx1[NA], gx2[NA], gy1[NA], gy2[NA];     // gt box corners
    float gobj[NA];
#pragma unroll
    for (int a = 0; a < NA; ++a) {
        const float* pa = P + a * STRIDE;
        const float* ta = T + a * STRIDE;
        sx[a]  = sigmoidf(pa[0]);
        sy[a]  = sigmoidf(pa[1]);
        ptw[a] = pa[2];
        pth[a] = pa[3];
        pto[a] = pa[4];
        float pw = expf(pa[2]) * AW[a];
        float ph = expf(pa[3]) * AH[a];
        px1[a] = sx[a] - pw * 0.5f; px2[a] = sx[a] + pw * 0.5f;
        py1[a] = sy[a] - ph * 0.5f; py2[a] = sy[a] + ph * 0.5f;
        gx[a] = ta[0]; gy[a] = ta[1];
        float gw = expf(ta[2]) * AW[a];
        float gh = expf(ta[3]) * AH[a];
        gx1[a] = gx[a] - gw * 0.5f; gx2[a] = gx[a] + gw * 0.5f;
        gy1[a] = gy[a] - gh * 0.5f; gy2[a] = gy[a] + gh * 0.5f;
        gobj[a] = ta[4];
    }

    // ---- pairwise IoU (g = gt slot, p = pred anchor)
    float iou[NA][NA];
#pragma unroll
    for (int g = 0; g < NA; ++g) {
        float gA = (gx2[g] - gx1[g]) * (gy2[g] - gy1[g]);
#pragma unroll
        for (int p = 0; p < NA; ++p) {
            float iw = fmaxf(fminf(gx2[g], px2[p]) - fmaxf(gx1[g], px1[p]), 0.0f);
            float ih = fmaxf(fminf(gy2[g], py2[p]) - fmaxf(gy1[g], py1[p]), 0.0f);
            float inter = iw * ih;
            float pA = (px2[p] - px1[p]) * (py2[p] - py1[p]);
            float uni = gA + pA - inter + 1e-9f;
            iou[g][p] = inter / uni;
        }
    }

    // ---- greedy matching (first-occurrence argmax, taken masked to -1)
    int assign[NA] = {-1, -1, -1, -1, -1};
    bool taken[NA] = {false, false, false, false, false};
#pragma unroll
    for (int g = 0; g < NA; ++g) {
        if (gobj[g] > 0.5f) {
            float best = -2.0f; int bi = 0;
#pragma unroll
            for (int p = 0; p < NA; ++p) {
                float v = taken[p] ? -1.0f : iou[g][p];
                if (v > best) { best = v; bi = p; }
            }
            taken[bi] = true;
            assign[bi] = g;
        }
    }

    // ---- losses
    float l_xy = 0.f, l_wh = 0.f, l_obj = 0.f, l_noobj = 0.f, l_cls = 0.f;
#pragma unroll
    for (int p = 0; p < NA; ++p) {
        const int g = assign[p];    // wave-uniform
        if (g >= 0) {
            const float* tg = T + g * STRIDE;
            float dx = sx[p] - tg[0];
            float dy = sy[p] - tg[1];
            l_xy += dx * dx + dy * dy;
            float dw = ptw[p] - tg[2];
            float dh = pth[p] - tg[3];
            l_wh += dw * dw + dh * dh;
            l_obj += softplusf(-pto[p]);

            // cls NLL: logsumexp over 80 pred logits, label = argmax of 80 gt vals
            const float* pc = P + p * STRIDE + 5;
            const float* tc = tg + 5;
            float v0 = pc[lane];
            float v1 = (lane < 16) ? pc[64 + lane] : -INFINITY;
            float m = waveMax(fmaxf(v0, v1));
            float s = expf(v0 - m) + ((lane < 16) ? expf(v1 - m) : 0.0f);
            s = waveSum(s);
            float lse = m + logf(s);

            float bv = tc[lane]; int bi = lane;
            if (lane < 16) {
                float v2 = tc[64 + lane];
                if (v2 > bv) { bv = v2; bi = 64 + lane; }
            }
#pragma unroll
            for (int o = 32; o; o >>= 1) {
                float ov = __shfl_xor(bv, o);
                int   oi = __shfl_xor(bi, o);
                if (ov > bv || (ov == bv && oi < bi)) { bv = ov; bi = oi; }
            }
            l_cls += lse - pc[bi];
        } else {
            l_noobj += softplusf(pto[p]);
        }
    }

    float cellLoss = 5.0f * l_xy + 5.0f * l_wh + 1.0f * l_obj
                   + 0.5f * l_noobj + 1.0f * l_cls;
    if (lane == 0) wsum[w] = cellLoss;
    __syncthreads();
    if (tid == 0) {
        atomicAdd(out, (wsum[0] + wsum[1] + wsum[2] + wsum[3]) * (1.0f / (float)NIMG));
    }
}

extern "C" void kernel_launch(void* const* d_in, const int* in_sizes, int n_in,
                              void* d_out, int out_size, void* d_ws, size_t ws_size,
                              hipStream_t stream) {
    const float* pred   = (const float*)d_in[0];
    const float* target = (const float*)d_in[1];
    float* out = (float*)d_out;
    hipMemsetAsync(out, 0, (size_t)out_size * sizeof(float), stream);
    yolo_loss_kernel<<<NCELLS / CPB, 256, 0, stream>>>(pred, target, out);
}